// Round 1
// baseline (414.164 us; speedup 1.0000x reference)
//
#include <hip/hip_runtime.h>
#include <cstdint>
#include <cstddef>

#define NB 4
#define NL 5
#define NC 256
#define NH 96
#define NW 192
#define NHW (NH * NW)
#define THRE 0.01f

// ---------------- conf: sigmoid(rm).max over anchors ----------------
__global__ __launch_bounds__(256) void conf_kernel(const float* __restrict__ rm,
                                                   float* __restrict__ conf,
                                                   float* __restrict__ counter) {
    int i = blockIdx.x * 256 + threadIdx.x;
    if (i == 0) *counter = 0.0f;
    if (i >= NB * NL * NHW) return;
    int n = i / NHW, p = i - n * NHW;
    float a = rm[((size_t)n * 2 + 0) * NHW + p];
    float b = rm[((size_t)n * 2 + 1) * NHW + p];
    float sa = 1.0f / (1.0f + expf(-a));
    float sb = 1.0f / (1.0f + expf(-b));
    conf[i] = fmaxf(sa, sb);
}

// ---------------- mask: 5x5 gaussian conv (zero pad) + threshold ----------------
__global__ __launch_bounds__(256) void mask_kernel(const float* __restrict__ conf,
                                                   const float* __restrict__ g,
                                                   float* __restrict__ mask,
                                                   float* __restrict__ counter) {
    int i = blockIdx.x * 256 + threadIdx.x;
    if (i >= NB * NL * NHW) return;
    int n = i / NHW, p = i - n * NHW;
    int h = p / NW, w = p - h * NW;
    float s = 0.0f;
#pragma unroll
    for (int ky = 0; ky < 5; ky++) {
        int y = h + ky - 2;
        if (y < 0 || y >= NH) continue;
#pragma unroll
        for (int kx = 0; kx < 5; kx++) {
            int x = w + kx - 2;
            if (x < 0 || x >= NW) continue;
            s += conf[(size_t)n * NHW + y * NW + x] * g[ky * 5 + kx];
        }
    }
    float m = (s > THRE) ? 1.0f : 0.0f;
    mask[i] = m;

    // comm_rate accumulation: only images with l==0 (n % NL == 0)
    float cnt = (n % NL == 0) ? m : 0.0f;
#pragma unroll
    for (int off = 32; off; off >>= 1) cnt += __shfl_down(cnt, off, 64);
    if ((threadIdx.x & 63) == 0 && cnt != 0.0f) atomicAdd(counter, cnt);
}

// ---------------- main fused kernel ----------------
// grid: NB * (NHW/64) blocks, 256 threads (4 waves).
// wave lane  -> one of 64 consecutive pixels
// wave index -> one of 4 groups of 64 channels
__global__ __launch_bounds__(256) void fuse_kernel(const float* __restrict__ x,
                                                   const float* __restrict__ M,
                                                   const float* __restrict__ mask,
                                                   float* __restrict__ out) {
    const int tid = threadIdx.x;
    const int wid = tid >> 6;
    const int lane = tid & 63;
    const int blocksPerB = NHW / 64; // 288
    const int b = blockIdx.x / blocksPerB;
    const int p = (blockIdx.x % blocksPerB) * 64 + lane;
    const int h = p / NW, w = p - h * NW;

    const float gx = (w + 0.5f) * (2.0f / NW) - 1.0f;
    const float gy = (h + 0.5f) * (2.0f / NH) - 1.0f;

    const float s01 = (float)NH / (float)NW;          // 0.5
    const float s02 = 2.0f / (0.4f * (float)NW);
    const float s10 = (float)NW / (float)NH;          // 2.0
    const float s12 = 2.0f / (0.4f * (float)NH);

    float wt[NL][4];
    int   off[NL][4];

#pragma unroll
    for (int m = 0; m < NL; m++) {
        const float* Mb = M + ((size_t)(b * NL) * NL + m) * 16;
        float th00 = Mb[0];
        float th01 = Mb[1] * s01;
        float th02 = Mb[3] * s02;
        float th10 = Mb[4] * s10;
        float th11 = Mb[5];
        float th12 = Mb[7] * s12;
        float pxn = th00 * gx + th01 * gy + th02;
        float pyn = th10 * gx + th11 * gy + th12;
        float sx = ((pxn + 1.0f) * (float)NW - 1.0f) * 0.5f;
        float sy = ((pyn + 1.0f) * (float)NH - 1.0f) * 0.5f;
        float x0 = floorf(sx), y0 = floorf(sy);
        float fx = sx - x0, fy = sy - y0;
        float xs[2] = {x0, x0 + 1.0f};
        float ys[2] = {y0, y0 + 1.0f};
        float wxv[2] = {1.0f - fx, fx};
        float wyv[2] = {1.0f - fy, fy};
#pragma unroll
        for (int ty = 0; ty < 2; ty++) {
#pragma unroll
            for (int tx = 0; tx < 2; tx++) {
                int t = ty * 2 + tx;
                float xf = xs[tx], yf = ys[ty];
                bool valid = (xf >= 0.0f) && (xf <= (float)(NW - 1)) &&
                             (yf >= 0.0f) && (yf <= (float)(NH - 1));
                int ix = (int)fminf(fmaxf(xf, 0.0f), (float)(NW - 1));
                int iy = (int)fminf(fmaxf(yf, 0.0f), (float)(NH - 1));
                int o = iy * NW + ix;
                float mv = (m == 0) ? 1.0f : mask[(size_t)(b * NL + m) * NHW + o];
                wt[m][t] = wxv[tx] * wyv[ty] * (valid ? mv : 0.0f);
                off[m][t] = o;
            }
        }
    }

    const float* Xb = x + (size_t)b * NL * NC * NHW;
    const int c0 = wid * 64;

    // pass 1: partial dots over this wave's 64 channels
    float dot[NL] = {0.f, 0.f, 0.f, 0.f, 0.f};
    for (int i = 0; i < 64; i++) {
        int c = c0 + i;
        float v[NL];
#pragma unroll
        for (int m = 0; m < NL; m++) {
            const float* pl = Xb + (size_t)(m * NC + c) * NHW;
            v[m] = wt[m][0] * pl[off[m][0]] + wt[m][1] * pl[off[m][1]] +
                   wt[m][2] * pl[off[m][2]] + wt[m][3] * pl[off[m][3]];
        }
#pragma unroll
        for (int m = 0; m < NL; m++) dot[m] += v[0] * v[m];
    }

    __shared__ float sdot[4][64][NL];
#pragma unroll
    for (int m = 0; m < NL; m++) sdot[wid][lane][m] = dot[m];
    __syncthreads();

    float d[NL];
#pragma unroll
    for (int m = 0; m < NL; m++)
        d[m] = (sdot[0][lane][m] + sdot[1][lane][m] + sdot[2][lane][m] + sdot[3][lane][m]) * (1.0f / 16.0f);

    float mx = d[0];
#pragma unroll
    for (int m = 1; m < NL; m++) mx = fmaxf(mx, d[m]);
    float pw[NL], sum = 0.0f;
#pragma unroll
    for (int m = 0; m < NL; m++) { pw[m] = expf(d[m] - mx); sum += pw[m]; }
    float inv = 1.0f / sum;
#pragma unroll
    for (int m = 0; m < NL; m++) pw[m] *= inv;

    // pass 2: recompute samples (L1/L2 warm) and emit fused output
    for (int i = 0; i < 64; i++) {
        int c = c0 + i;
        float acc = 0.0f;
#pragma unroll
        for (int m = 0; m < NL; m++) {
            const float* pl = Xb + (size_t)(m * NC + c) * NHW;
            float v = wt[m][0] * pl[off[m][0]] + wt[m][1] * pl[off[m][1]] +
                      wt[m][2] * pl[off[m][2]] + wt[m][3] * pl[off[m][3]];
            acc += pw[m] * v;
        }
        out[((size_t)b * NC + c) * NHW + p] = acc;
    }
}

// ---------------- finalize comm_rate ----------------
__global__ void finalize_kernel(const float* __restrict__ counter, float* __restrict__ out) {
    out[(size_t)NB * NC * NHW] = *counter / (float)(NB * NHW);
}

extern "C" void kernel_launch(void* const* d_in, const int* in_sizes, int n_in,
                              void* d_out, int out_size, void* d_ws, size_t ws_size,
                              hipStream_t stream) {
    const float* x  = (const float*)d_in[0];
    const float* rm = (const float*)d_in[1];
    const float* M  = (const float*)d_in[2];
    const float* g  = (const float*)d_in[3];
    float* out = (float*)d_out;

    float* conf    = (float*)d_ws;                       // NB*NL*NHW floats
    float* mask    = conf + (size_t)NB * NL * NHW;       // NB*NL*NHW floats
    float* counter = mask + (size_t)NB * NL * NHW;       // 1 float

    const int total = NB * NL * NHW;                     // 368640
    const int blk = 256;

    conf_kernel<<<(total + blk - 1) / blk, blk, 0, stream>>>(rm, conf, counter);
    mask_kernel<<<(total + blk - 1) / blk, blk, 0, stream>>>(conf, g, mask, counter);
    fuse_kernel<<<NB * (NHW / 64), blk, 0, stream>>>(x, M, mask, out);
    finalize_kernel<<<1, 1, 0, stream>>>(counter, out);
}

// Round 2
// 318.764 us; speedup vs baseline: 1.2993x; 1.2993x over previous
//
#include <hip/hip_runtime.h>
#include <hip/hip_fp16.h>
#include <cstdint>
#include <cstddef>

#define NB 4
#define NL 5
#define NC 256
#define NH 96
#define NW 192
#define NHW (NH * NW)
#define NPIX (NB * NHW)   // 73728
#define PGRP (NHW / 64)   // 288
#define THRE 0.01f

// ---------------- per-pixel bilinear tap weights/offsets (mask folded in) ----
__device__ __forceinline__ void compute_taps(const float* __restrict__ M,
                                             const float* __restrict__ mask,
                                             int b, int p,
                                             float wt[NL][4], int off[NL][4]) {
    const int h = p / NW, w = p - h * NW;
    const float gx = (w + 0.5f) * (2.0f / NW) - 1.0f;
    const float gy = (h + 0.5f) * (2.0f / NH) - 1.0f;
    const float s01 = (float)NH / (float)NW;
    const float s02 = 2.0f / (0.4f * (float)NW);
    const float s10 = (float)NW / (float)NH;
    const float s12 = 2.0f / (0.4f * (float)NH);
#pragma unroll
    for (int m = 0; m < NL; m++) {
        const float* Mb = M + ((size_t)(b * NL) * NL + m) * 16;
        float th00 = Mb[0];
        float th01 = Mb[1] * s01;
        float th02 = Mb[3] * s02;
        float th10 = Mb[4] * s10;
        float th11 = Mb[5];
        float th12 = Mb[7] * s12;
        float pxn = th00 * gx + th01 * gy + th02;
        float pyn = th10 * gx + th11 * gy + th12;
        float sx = ((pxn + 1.0f) * (float)NW - 1.0f) * 0.5f;
        float sy = ((pyn + 1.0f) * (float)NH - 1.0f) * 0.5f;
        float x0 = floorf(sx), y0 = floorf(sy);
        float fx = sx - x0, fy = sy - y0;
        float xs[2] = {x0, x0 + 1.0f};
        float ys[2] = {y0, y0 + 1.0f};
        float wxv[2] = {1.0f - fx, fx};
        float wyv[2] = {1.0f - fy, fy};
#pragma unroll
        for (int ty = 0; ty < 2; ty++) {
#pragma unroll
            for (int tx = 0; tx < 2; tx++) {
                int t = ty * 2 + tx;
                float xf = xs[tx], yf = ys[ty];
                bool valid = (xf >= 0.0f) && (xf <= (float)(NW - 1)) &&
                             (yf >= 0.0f) && (yf <= (float)(NH - 1));
                int ix = (int)fminf(fmaxf(xf, 0.0f), (float)(NW - 1));
                int iy = (int)fminf(fmaxf(yf, 0.0f), (float)(NH - 1));
                int o = iy * NW + ix;
                float mv = (m == 0) ? 1.0f : mask[(size_t)(b * NL + m) * NHW + o];
                wt[m][t] = wxv[tx] * wyv[ty] * (valid ? mv : 0.0f);
                off[m][t] = o;
            }
        }
    }
}

// ---------------- conf: sigmoid(rm).max over anchors ----------------
__global__ __launch_bounds__(256) void conf_kernel(const float* __restrict__ rm,
                                                   float* __restrict__ conf,
                                                   float* __restrict__ counter) {
    int i = blockIdx.x * 256 + threadIdx.x;
    if (i == 0) *counter = 0.0f;
    if (i >= NB * NL * NHW) return;
    int n = i / NHW, p = i - n * NHW;
    float a = rm[((size_t)n * 2 + 0) * NHW + p];
    float b = rm[((size_t)n * 2 + 1) * NHW + p];
    float sa = 1.0f / (1.0f + expf(-a));
    float sb = 1.0f / (1.0f + expf(-b));
    conf[i] = fmaxf(sa, sb);
}

// ---------------- mask: 5x5 gaussian conv (zero pad) + threshold ----------------
__global__ __launch_bounds__(256) void mask_kernel(const float* __restrict__ conf,
                                                   const float* __restrict__ g,
                                                   float* __restrict__ mask,
                                                   float* __restrict__ counter) {
    int i = blockIdx.x * 256 + threadIdx.x;
    if (i >= NB * NL * NHW) return;
    int n = i / NHW, p = i - n * NHW;
    int h = p / NW, w = p - h * NW;
    float s = 0.0f;
#pragma unroll
    for (int ky = 0; ky < 5; ky++) {
        int y = h + ky - 2;
        if (y < 0 || y >= NH) continue;
#pragma unroll
        for (int kx = 0; kx < 5; kx++) {
            int x = w + kx - 2;
            if (x < 0 || x >= NW) continue;
            s += conf[(size_t)n * NHW + y * NW + x] * g[ky * 5 + kx];
        }
    }
    float m = (s > THRE) ? 1.0f : 0.0f;
    mask[i] = m;
    float cnt = (n % NL == 0) ? m : 0.0f;
#pragma unroll
    for (int off = 32; off; off >>= 1) cnt += __shfl_down(cnt, off, 64);
    if ((threadIdx.x & 63) == 0 && cnt != 0.0f) atomicAdd(counter, cnt);
}

// ---------------- sample + partial dots (one pass over x) ----------------
// grid: (b, pgroup, cchunk) -> NB*288*4 blocks. 256 thr = 4 waves.
// lane = pixel (64 consecutive), wave = 16 channels of the 64-channel chunk.
template<bool STOREV>
__global__ __launch_bounds__(256) void sample_dot_kernel(
        const float* __restrict__ x, const float* __restrict__ M,
        const float* __restrict__ mask, float* __restrict__ dots4,
        __half* __restrict__ vbuf) {
    const int tid = threadIdx.x, wid = tid >> 6, lane = tid & 63;
    const int cc = blockIdx.x & 3;
    const int bp = blockIdx.x >> 2;            // b*288 + pg
    const int b = bp / PGRP;
    const int p = (bp - b * PGRP) * 64 + lane;

    float wt[NL][4]; int off[NL][4];
    compute_taps(M, mask, b, p, wt, off);

    const float* Xb = x + (size_t)b * NL * NC * NHW;
    const int c0 = cc * 64 + wid * 16;
    float dot[NL] = {0.f, 0.f, 0.f, 0.f, 0.f};
    for (int i = 0; i < 16; i++) {
        int c = c0 + i;
        float v[NL];
#pragma unroll
        for (int m = 0; m < NL; m++) {
            const float* pl = Xb + (size_t)(m * NC + c) * NHW;
            v[m] = wt[m][0] * pl[off[m][0]] + wt[m][1] * pl[off[m][1]] +
                   wt[m][2] * pl[off[m][2]] + wt[m][3] * pl[off[m][3]];
        }
        if (STOREV) {
#pragma unroll
            for (int m = 0; m < NL; m++)
                vbuf[((size_t)(b * NL + m) * NC + c) * NHW + p] = __float2half(v[m]);
        }
#pragma unroll
        for (int m = 0; m < NL; m++) dot[m] += v[0] * v[m];
    }

    __shared__ float sd[4][64][NL];
#pragma unroll
    for (int m = 0; m < NL; m++) sd[wid][lane][m] = dot[m];
    __syncthreads();
    if (wid == 0) {
#pragma unroll
        for (int m = 0; m < NL; m++) {
            float s = sd[0][lane][m] + sd[1][lane][m] + sd[2][lane][m] + sd[3][lane][m];
            dots4[((size_t)cc * NPIX + (size_t)bp * 64 + lane) * NL + m] = s;
        }
    }
}

// ---------------- per-pixel softmax -> transposed weights ----------------
__global__ __launch_bounds__(256) void softmax_kernel(const float* __restrict__ dots4,
                                                      float* __restrict__ pwT) {
    int i = blockIdx.x * 256 + threadIdx.x;
    if (i >= NPIX) return;
    float d[NL];
#pragma unroll
    for (int m = 0; m < NL; m++)
        d[m] = (dots4[((size_t)0 * NPIX + i) * NL + m] +
                dots4[((size_t)1 * NPIX + i) * NL + m] +
                dots4[((size_t)2 * NPIX + i) * NL + m] +
                dots4[((size_t)3 * NPIX + i) * NL + m]) * (1.0f / 16.0f);
    float mx = d[0];
#pragma unroll
    for (int m = 1; m < NL; m++) mx = fmaxf(mx, d[m]);
    float pw[NL], sum = 0.0f;
#pragma unroll
    for (int m = 0; m < NL; m++) { pw[m] = expf(d[m] - mx); sum += pw[m]; }
    float inv = 1.0f / sum;
#pragma unroll
    for (int m = 0; m < NL; m++) pwT[(size_t)m * NPIX + i] = pw[m] * inv;
}

// ---------------- streaming output: out = sum_m pw[m] * v[m] ----------------
__global__ __launch_bounds__(256) void out_stream_kernel(const __half* __restrict__ vbuf,
                                                         const float* __restrict__ pwT,
                                                         float* __restrict__ out) {
    size_t idx = ((size_t)blockIdx.x * 256 + threadIdx.x) * 4;   // 4 pixels/thread
    int p = (int)(idx % NHW);
    int c = (int)((idx / NHW) % NC);
    int b = (int)(idx / ((size_t)NHW * NC));
    size_t pix = (size_t)b * NHW + p;
    float4 acc = {0.f, 0.f, 0.f, 0.f};
#pragma unroll
    for (int m = 0; m < NL; m++) {
        float4 w4 = *reinterpret_cast<const float4*>(pwT + (size_t)m * NPIX + pix);
        union { uint2 u; __half h[4]; } V;
        V.u = *reinterpret_cast<const uint2*>(vbuf + ((size_t)(b * NL + m) * NC + c) * NHW + p);
        acc.x += w4.x * __half2float(V.h[0]);
        acc.y += w4.y * __half2float(V.h[1]);
        acc.z += w4.z * __half2float(V.h[2]);
        acc.w += w4.w * __half2float(V.h[3]);
    }
    *reinterpret_cast<float4*>(out + idx) = acc;
}

// ---------------- fallback output (no vbuf): re-gather x ----------------
__global__ __launch_bounds__(256) void out_gather_kernel(const float* __restrict__ x,
                                                         const float* __restrict__ M,
                                                         const float* __restrict__ mask,
                                                         const float* __restrict__ pwT,
                                                         float* __restrict__ out) {
    size_t idx = (size_t)blockIdx.x * 256 + threadIdx.x;  // one (b,c,p)
    int p = (int)(idx % NHW);
    size_t t = idx / NHW;
    int c = (int)(t % NC);
    int b = (int)(t / NC);
    float wt[NL][4]; int off[NL][4];
    compute_taps(M, mask, b, p, wt, off);
    const float* Xb = x + (size_t)b * NL * NC * NHW;
    float acc = 0.0f;
#pragma unroll
    for (int m = 0; m < NL; m++) {
        const float* pl = Xb + (size_t)(m * NC + c) * NHW;
        float v = wt[m][0] * pl[off[m][0]] + wt[m][1] * pl[off[m][1]] +
                  wt[m][2] * pl[off[m][2]] + wt[m][3] * pl[off[m][3]];
        acc += pwT[(size_t)m * NPIX + (size_t)b * NHW + p] * v;
    }
    out[idx] = acc;
}

// ---------------- finalize comm_rate ----------------
__global__ void finalize_kernel(const float* __restrict__ counter, float* __restrict__ out) {
    out[(size_t)NB * NC * NHW] = *counter / (float)(NB * NHW);
}

extern "C" void kernel_launch(void* const* d_in, const int* in_sizes, int n_in,
                              void* d_out, int out_size, void* d_ws, size_t ws_size,
                              hipStream_t stream) {
    const float* x  = (const float*)d_in[0];
    const float* rm = (const float*)d_in[1];
    const float* M  = (const float*)d_in[2];
    const float* g  = (const float*)d_in[3];
    float* out = (float*)d_out;

    float* conf    = (float*)d_ws;                        // NB*NL*NHW
    float* mask    = conf + (size_t)NB * NL * NHW;        // NB*NL*NHW
    float* dots4   = mask + (size_t)NB * NL * NHW;        // 4*NPIX*NL
    float* pwT     = dots4 + (size_t)4 * NPIX * NL;       // NL*NPIX
    float* counter = pwT + (size_t)NL * NPIX;             // 1 (+pad 16)
    __half* vbuf   = (__half*)(counter + 16);             // NB*NL*NC*NHW halves

    size_t base_bytes = (size_t)((char*)(counter + 16) - (char*)d_ws);
    size_t vbuf_bytes = (size_t)NB * NL * NC * NHW * sizeof(__half);
    bool storev = ws_size >= base_bytes + vbuf_bytes;

    const int total = NB * NL * NHW;
    const int blk = 256;

    conf_kernel<<<(total + blk - 1) / blk, blk, 0, stream>>>(rm, conf, counter);
    mask_kernel<<<(total + blk - 1) / blk, blk, 0, stream>>>(conf, g, mask, counter);

    if (storev) {
        sample_dot_kernel<true><<<NB * PGRP * 4, blk, 0, stream>>>(x, M, mask, dots4, vbuf);
        softmax_kernel<<<(NPIX + blk - 1) / blk, blk, 0, stream>>>(dots4, pwT);
        out_stream_kernel<<<(NB * NC * NHW) / (blk * 4), blk, 0, stream>>>(vbuf, pwT, out);
    } else {
        sample_dot_kernel<false><<<NB * PGRP * 4, blk, 0, stream>>>(x, M, mask, dots4, nullptr);
        softmax_kernel<<<(NPIX + blk - 1) / blk, blk, 0, stream>>>(dots4, pwT);
        out_gather_kernel<<<(NB * NC * NHW) / blk, blk, 0, stream>>>(x, M, mask, pwT, out);
    }
    finalize_kernel<<<1, 1, 0, stream>>>(counter, out);
}